// Round 10
// baseline (246.618 us; speedup 1.0000x reference)
//
#include <hip/hip_runtime.h>
#include <hip/hip_bf16.h>

// DeepViT re-attention, fused flash-style two-pass.
//  k0 convert3 : x, w_qkv, w_out fp32 -> bf16 (ws)
//  k1 gemm_qkv : qkv = x @ w_qkv^T (bf16 MFMA); scatter q(scaled)/k/vT bf16
//  (memset)    : zero inner_f32 accumulator (reuses xb/wqb region)
//  k2 passA    : softmax stats (m, l), j-split x4
//  k3 passB    : 256-thr / waves_per_eu(3) (VGPR budget ~170: R7-R9 showed the
//                128-budget allocator squeezes to 52-64 and serializes all
//                batched loads). Fused 4-way stats merge; Q in LDS; batched K
//                loads; v_pk_fma_f32 g-paired mix; pk LN; paired cvt_pk_bf16;
//                PV (2 heads/wave); f32 atomicAdd partials (4 contributions).
//  k3b convert : inner_f32 -> bf16
//  k4 gemm_out : out = inner @ w_out^T + b_out (fp32)

typedef __attribute__((ext_vector_type(8))) short bfx8;
typedef __attribute__((ext_vector_type(4))) float f32x4;
typedef __attribute__((ext_vector_type(2))) float f32x2;
typedef unsigned short u16;
typedef unsigned int u32;

#define QSCALE 0.18033688011112042f  /* (1/8) * log2(e) */

static __device__ inline u16 f2bf(float f) {
  union { float f; unsigned u; } cv; cv.f = f;
  unsigned u = cv.u;
  u += 0x7fffu + ((u >> 16) & 1u);   // RNE
  return (u16)(u >> 16);
}
static __device__ inline u32 cvtpk(float lo, float hi) {  // {bf16(lo), bf16(hi)}
  u32 d; asm("v_cvt_pk_bf16_f32 %0, %1, %2" : "=v"(d) : "v"(lo), "v"(hi)); return d;
}
static __device__ inline float fexp2(float x) {
  float r; asm("v_exp_f32 %0, %1" : "=v"(r) : "v"(x)); return r;
}
static __device__ inline float flog2(float x) {
  float r; asm("v_log_f32 %0, %1" : "=v"(r) : "v"(x)); return r;
}

// ---------------- k0: fp32 -> bf16 converts ----------------
__global__ __launch_bounds__(256) void convert3(
    const float* __restrict__ x, const float* __restrict__ wq,
    const float* __restrict__ wo,
    u16* __restrict__ xb, u16* __restrict__ wqb, u16* __restrict__ wob) {
  int e = (blockIdx.x * 256 + threadIdx.x) * 4;
  const float* src; u16* dst; int off;
  if (e < 2097152)      { src = x;  dst = xb;  off = e; }
  else if (e < 2883584) { src = wq; dst = wqb; off = e - 2097152; }
  else                  { src = wo; dst = wob; off = e - 2883584; }
  float4 v = *(const float4*)&src[off];
  ushort4 o; o.x = f2bf(v.x); o.y = f2bf(v.y); o.z = f2bf(v.z); o.w = f2bf(v.w);
  *(ushort4*)&dst[off] = o;
}

// ---------------- k1: bf16 GEMM, C = A @ B^T, QKV scatter epilogue ----------------
__global__ __launch_bounds__(256) void gemm_qkv(
    const u16* __restrict__ A, const u16* __restrict__ B,
    u16* __restrict__ qb, u16* __restrict__ kb, u16* __restrict__ vtb) {
  __shared__ u16 As[128 * 32];
  __shared__ u16 Bs[128 * 32];
  const int t = threadIdx.x, lane = t & 63;
  const int wm = (t >> 6) >> 1, wn = (t >> 6) & 1;
  const int m0 = blockIdx.y * 128, n0 = blockIdx.x * 128;
  const int li = lane & 15, lg = lane >> 4;
  const int rowA = t >> 2, kb8 = (t & 3) * 8;
  f32x4 acc[4][4] = {};
  for (int k0 = 0; k0 < 512; k0 += 32) {
    __syncthreads();
    *(bfx8*)&As[rowA * 32 + kb8]        = *(const bfx8*)&A[(size_t)(m0 + rowA) * 512 + k0 + kb8];
    *(bfx8*)&As[(rowA + 64) * 32 + kb8] = *(const bfx8*)&A[(size_t)(m0 + rowA + 64) * 512 + k0 + kb8];
    *(bfx8*)&Bs[rowA * 32 + kb8]        = *(const bfx8*)&B[(size_t)(n0 + rowA) * 512 + k0 + kb8];
    *(bfx8*)&Bs[(rowA + 64) * 32 + kb8] = *(const bfx8*)&B[(size_t)(n0 + rowA + 64) * 512 + k0 + kb8];
    __syncthreads();
    bfx8 af[4], bf_[4];
#pragma unroll
    for (int mi = 0; mi < 4; mi++)
      af[mi] = *(const bfx8*)&As[(wm * 64 + mi * 16 + li) * 32 + lg * 8];
#pragma unroll
    for (int ni = 0; ni < 4; ni++)
      bf_[ni] = *(const bfx8*)&Bs[(wn * 64 + ni * 16 + li) * 32 + lg * 8];
#pragma unroll
    for (int mi = 0; mi < 4; mi++)
#pragma unroll
      for (int ni = 0; ni < 4; ni++)
        acc[mi][ni] = __builtin_amdgcn_mfma_f32_16x16x32_bf16(af[mi], bf_[ni], acc[mi][ni], 0, 0, 0);
  }
#pragma unroll
  for (int mi = 0; mi < 4; mi++) {
#pragma unroll
    for (int ni = 0; ni < 4; ni++) {
      const int nc  = n0 + wn * 64 + ni * 16 + li;
      const int mrb = m0 + wm * 64 + mi * 16 + lg * 4;
      const int part = nc >> 9, within = nc & 511;
      const int h = within >> 6, d = within & 63;
      const int bb = mrb >> 11, ii = mrb & 2047;
      if (part == 0) {
#pragma unroll
        for (int r = 0; r < 4; r++)
          qb[(((size_t)bb * 8 + h) * 2048 + ii + r) * 64 + d] = f2bf(acc[mi][ni][r] * QSCALE);
      } else if (part == 1) {
#pragma unroll
        for (int r = 0; r < 4; r++)
          kb[(((size_t)bb * 8 + h) * 2048 + ii + r) * 64 + d] = f2bf(acc[mi][ni][r]);
      } else {
        ushort4 u;
        u.x = f2bf(acc[mi][ni][0]); u.y = f2bf(acc[mi][ni][1]);
        u.z = f2bf(acc[mi][ni][2]); u.w = f2bf(acc[mi][ni][3]);
        *(ushort4*)&vtb[(((size_t)bb * 8 + h) * 64 + d) * 2048 + ii] = u;
      }
    }
  }
}

// ---------------- k2: softmax stats (m, l), j-split x4, 2-tile batched ----------------
__global__ __launch_bounds__(256) void passA(
    const u16* __restrict__ qb, const u16* __restrict__ kb,
    float2* __restrict__ statp) {
  const int t = threadIdx.x, lane = t & 63, w = t >> 6;
  const int bh = blockIdx.y, js = blockIdx.z;
  const int i0 = blockIdx.x * 64 + w * 16;
  const int li = lane & 15, lg = lane >> 4;
  const u16* Qh = qb + ((size_t)bh * 2048 + i0 + li) * 64;
  const u16* Kb = kb + (size_t)bh * 2048 * 64;
  const bfx8 q0 = *(const bfx8*)&Qh[lg * 8];
  const bfx8 q1 = *(const bfx8*)&Qh[32 + lg * 8];
  float m = -1e30f, l = 0.f;
  const int jbeg = js * 512, jend = jbeg + 512;
  for (int j0 = jbeg; j0 < jend; j0 += 32) {
    const u16* KhA = Kb + (size_t)(j0 + li) * 64;
    const u16* KhB = KhA + 16 * 64;
    bfx8 a0 = *(const bfx8*)&KhA[lg * 8];
    bfx8 a1 = *(const bfx8*)&KhA[32 + lg * 8];
    bfx8 b0 = *(const bfx8*)&KhB[lg * 8];
    bfx8 b1 = *(const bfx8*)&KhB[32 + lg * 8];
    __builtin_amdgcn_sched_barrier(0);
    f32x4 sa = {0.f, 0.f, 0.f, 0.f}, sb = {0.f, 0.f, 0.f, 0.f};
    sa = __builtin_amdgcn_mfma_f32_16x16x32_bf16(a0, q0, sa, 0, 0, 0);
    sa = __builtin_amdgcn_mfma_f32_16x16x32_bf16(a1, q1, sa, 0, 0, 0);
    sb = __builtin_amdgcn_mfma_f32_16x16x32_bf16(b0, q0, sb, 0, 0, 0);
    sb = __builtin_amdgcn_mfma_f32_16x16x32_bf16(b1, q1, sb, 0, 0, 0);
    float mt = fmaxf(fmaxf(fmaxf(sa[0], sa[1]), fmaxf(sa[2], sa[3])),
                     fmaxf(fmaxf(sb[0], sb[1]), fmaxf(sb[2], sb[3])));
    float mn = fmaxf(m, mt);
    float es = (fexp2(sa[0] - mn) + fexp2(sa[1] - mn)) + (fexp2(sa[2] - mn) + fexp2(sa[3] - mn))
             + (fexp2(sb[0] - mn) + fexp2(sb[1] - mn)) + (fexp2(sb[2] - mn) + fexp2(sb[3] - mn));
    l = fmaf(l, fexp2(m - mn), es);
    m = mn;
  }
  for (int off = 16; off < 64; off <<= 1) {
    float mo = __shfl_xor(m, off, 64);
    float lo = __shfl_xor(l, off, 64);
    float mn = fmaxf(m, mo);
    l = l * fexp2(m - mn) + lo * fexp2(mo - mn);
    m = mn;
  }
  if (lane < 16) statp[(size_t)js * 32768 + (size_t)bh * 2048 + i0 + li] = make_float2(m, l);
}

// ---------------- k3: pass B ----------------
// grid (128, 2, 4): x = i-tile-of-16, y = b, z = j-quarter. 256 thr = 4 waves.
// Per 64-j macro iter: wave w owns j-slab w*16; QK^T all 8 heads -> p in-lane;
// pk-math mix+LN; A'' bf16 to LDS; PV: wave w handles heads {w, w+4}.
__global__ __launch_bounds__(256) __attribute__((amdgpu_waves_per_eu(3)))
void passB(
    const u16* __restrict__ qb, const u16* __restrict__ kb,
    const u16* __restrict__ vtb, const float2* __restrict__ statp,
    const float* __restrict__ Wmix, const float* __restrict__ lng,
    const float* __restrict__ lnb, float* __restrict__ innerF) {
  __shared__ __align__(16) u16 A2[8 * 16 * 72];   // 18KB [g][i][j<64], row pad 72
  __shared__ __align__(16) u16 Qs[8 * 16 * 72];   // 18KB [h][i][d], row pad 72
  const int t = threadIdx.x, lane = t & 63, w = t >> 6;
  const int b = blockIdx.y, i0 = blockIdx.x * 16;
  const int li = lane & 15, lg = lane >> 4;
  const int swz = (li & 7) << 3;

  // stage Q: 1024 16B-chunks, 4 per thread
#pragma unroll
  for (int cc = 0; cc < 4; cc++) {
    const int c = t + cc * 256;
    const int h = c >> 7, qi = (c >> 3) & 15, d8 = c & 7;
    bfx8 v = *(const bfx8*)&qb[(((size_t)(b * 8 + h)) * 2048 + i0 + qi) * 64 + d8 * 8];
    *(bfx8*)&Qs[(h * 16 + qi) * 72 + d8 * 8] = v;
  }

  // W columns pre-paired (SGPR pairs), LN params paired
  f32x2 wm2_[8][4], lg2_[4], lb2_[4];
#pragma unroll
  for (int h = 0; h < 8; h++)
#pragma unroll
    for (int gp = 0; gp < 4; gp++) {
      wm2_[h][gp][0] = Wmix[h * 8 + gp * 2];
      wm2_[h][gp][1] = Wmix[h * 8 + gp * 2 + 1];
    }
#pragma unroll
  for (int gp = 0; gp < 4; gp++) {
    lg2_[gp][0] = lng[gp * 2]; lg2_[gp][1] = lng[gp * 2 + 1];
    lb2_[gp][0] = lnb[gp * 2]; lb2_[gp][1] = lnb[gp * 2 + 1];
  }

  // fused stats merge over 4 j-split partials: M = m + log2(l)
  float stM[8];
#pragma unroll
  for (int h = 0; h < 8; h++) {
    const size_t idx = ((size_t)(b * 8 + h)) * 2048 + i0 + li;
    float m = -1e30f, l = 0.f;
#pragma unroll
    for (int z = 0; z < 4; z++) {
      const float2 a = statp[(size_t)z * 32768 + idx];
      const float mn = fmaxf(m, a.x);
      l = l * fexp2(m - mn) + a.y * fexp2(a.x - mn);
      m = mn;
    }
    stM[h] = m + flog2(l);
  }

  __syncthreads();  // Qs ready

  f32x4 pacc[2][4] = {};
  const int jmb = blockIdx.z * 512;
  const size_t hstr = (size_t)2048 * 64;
  for (int jm = jmb; jm < jmb + 512; jm += 64) {
    const int j0 = jm + w * 16;
    const u16* Kb0 = kb + ((size_t)(b * 8) * 2048 + j0 + li) * 64;
    float p[8][4];
    // 2 half-batches of 4 heads: 8 K-loads in flight, pinned by sched_barrier
#pragma unroll
    for (int hb = 0; hb < 2; hb++) {
      bfx8 kf[4][2];
#pragma unroll
      for (int hh = 0; hh < 4; hh++) {
        const u16* Kh = Kb0 + (size_t)(hb * 4 + hh) * hstr;
        kf[hh][0] = *(const bfx8*)&Kh[lg * 8];
        kf[hh][1] = *(const bfx8*)&Kh[32 + lg * 8];
      }
      __builtin_amdgcn_sched_barrier(0);
#pragma unroll
      for (int hh = 0; hh < 4; hh++) {
        const int h = hb * 4 + hh;
        const bfx8 qA = *(const bfx8*)&Qs[(h * 16 + li) * 72 + lg * 8];
        const bfx8 qB = *(const bfx8*)&Qs[(h * 16 + li) * 72 + 32 + lg * 8];
        f32x4 s = {0.f, 0.f, 0.f, 0.f};
        s = __builtin_amdgcn_mfma_f32_16x16x32_bf16(kf[hh][0], qA, s, 0, 0, 0);
        s = __builtin_amdgcn_mfma_f32_16x16x32_bf16(kf[hh][1], qB, s, 0, 0, 0);
#pragma unroll
        for (int r = 0; r < 4; r++) p[h][r] = fexp2(s[r] - stM[h]);
      }
    }
    // mix + LN: g-paired packed math (v_pk_fma_f32), paired cvt_pk_bf16
    u32 apk[8][2];
    float tmp[8];
#pragma unroll
    for (int r = 0; r < 4; r++) {
      f32x2 a2g[4] = {{0.f, 0.f}, {0.f, 0.f}, {0.f, 0.f}, {0.f, 0.f}};
#pragma unroll
      for (int h = 0; h < 8; h++) {
        f32x2 pb; pb[0] = p[h][r]; pb[1] = p[h][r];
#pragma unroll
        for (int gp = 0; gp < 4; gp++)
          asm("v_pk_fma_f32 %0, %1, %2, %0" : "+v"(a2g[gp]) : "s"(wm2_[h][gp]), "v"(pb));
      }
      f32x2 sum2 = (a2g[0] + a2g[1]) + (a2g[2] + a2g[3]);
      f32x2 sq2 = a2g[0] * a2g[0] + a2g[1] * a2g[1];
      sq2 = sq2 + a2g[2] * a2g[2] + a2g[3] * a2g[3];
      const float sum = sum2[0] + sum2[1];
      const float sumsq = sq2[0] + sq2[1];
      const float mu = sum * 0.125f;
      const float var = fmaf(sumsq, 0.125f, -mu * mu);
      const float rs = rsqrtf(var + 1e-5f);
      f32x2 mu2; mu2[0] = mu; mu2[1] = mu;
      f32x2 rs2; rs2[0] = rs; rs2[1] = rs;
#pragma unroll
      for (int gp = 0; gp < 4; gp++) {
        f32x2 av = (a2g[gp] - mu2) * rs2;
        av = av * lg2_[gp] + lb2_[gp];
        if (r & 1) {
          apk[gp * 2][r >> 1]     = cvtpk(tmp[gp * 2], av[0]);
          apk[gp * 2 + 1][r >> 1] = cvtpk(tmp[gp * 2 + 1], av[1]);
        } else {
          tmp[gp * 2] = av[0]; tmp[gp * 2 + 1] = av[1];
        }
      }
    }
    {
      const int jsw = (w * 16 + lg * 4) ^ swz;   // 4 consecutive j per lane
#pragma unroll
      for (int g = 0; g < 8; g++)
        *(uint2*)&A2[(g * 16 + li) * 72 + jsw] = make_uint2(apk[g][0], apk[g][1]);
    }
    // V loads for head w issued BEFORE the barrier: latency under barrier drain
    bfx8 vF[2][4];
    {
      const u16* Vh = vtb + ((size_t)(b * 8 + w)) * 64 * 2048 + jm;
#pragma unroll
      for (int kc = 0; kc < 2; kc++)
#pragma unroll
        for (int nd = 0; nd < 4; nd++)
          vF[kc][nd] = *(const bfx8*)&Vh[(size_t)(nd * 16 + li) * 2048 + kc * 32 + lg * 8];
    }
    __syncthreads();
#pragma unroll
    for (int hh = 0; hh < 2; hh++) {
      const int hd = w + hh * 4;
      if (hh == 1) {
        const u16* Vh = vtb + ((size_t)(b * 8 + hd)) * 64 * 2048 + jm;
#pragma unroll
        for (int kc = 0; kc < 2; kc++)
#pragma unroll
          for (int nd = 0; nd < 4; nd++)
            vF[kc][nd] = *(const bfx8*)&Vh[(size_t)(nd * 16 + li) * 2048 + kc * 32 + lg * 8];
        __builtin_amdgcn_sched_barrier(0);
      }
      __builtin_amdgcn_s_setprio(1);
#pragma unroll
      for (int kc = 0; kc < 2; kc++) {
        const bfx8 af = *(const bfx8*)&A2[(hd * 16 + li) * 72 + ((kc * 32 + lg * 8) ^ swz)];
#pragma unroll
        for (int nd = 0; nd < 4; nd++)
          pacc[hh][nd] = __builtin_amdgcn_mfma_f32_16x16x32_bf16(af, vF[kc][nd], pacc[hh][nd], 0, 0, 0);
      }
      __builtin_amdgcn_s_setprio(0);
    }
    __syncthreads();
  }
#pragma unroll
  for (int hh = 0; hh < 2; hh++) {
    const int hd = w + hh * 4;
#pragma unroll
    for (int nd = 0; nd < 4; nd++)
#pragma unroll
      for (int r = 0; r < 4; r++)
        atomicAdd(&innerF[((size_t)b * 2048 + i0 + lg * 4 + r) * 512 + hd * 64 + nd * 16 + li],
                  pacc[hh][nd][r]);
  }
}

// ---------------- k3b: inner f32 -> bf16 ----------------
__global__ __launch_bounds__(256) void convertInner(
    const float* __restrict__ inF, u16* __restrict__ outB) {
  int e = (blockIdx.x * 256 + threadIdx.x) * 4;
  float4 v = *(const float4*)&inF[e];
  ushort4 o; o.x = f2bf(v.x); o.y = f2bf(v.y); o.z = f2bf(v.z); o.w = f2bf(v.w);
  *(ushort4*)&outB[e] = o;
}

// ---------------- k4: out = inner @ wo^T + b_out ----------------
__global__ __launch_bounds__(256) void gemm_out(
    const u16* __restrict__ A, const u16* __restrict__ B,
    float* __restrict__ outf, const float* __restrict__ bias) {
  __shared__ u16 As[128 * 32];
  __shared__ u16 Bs[128 * 32];
  const int t = threadIdx.x, lane = t & 63;
  const int wm = (t >> 6) >> 1, wn = (t >> 6) & 1;
  const int m0 = blockIdx.y * 128, n0 = blockIdx.x * 128;
  const int li = lane & 15, lg = lane >> 4;
  const int rowA = t >> 2, kb8 = (t & 3) * 8;
  f32x4 acc[4][4] = {};
  for (int k0 = 0; k0 < 512; k0 += 32) {
    __syncthreads();
    *(bfx8*)&As[rowA * 32 + kb8]        = *(const bfx8*)&A[(size_t)(m0 + rowA) * 512 + k0 + kb8];
    *(bfx8*)&As[(rowA + 64) * 32 + kb8] = *(const bfx8*)&A[(size_t)(m0 + rowA + 64) * 512 + k0 + kb8];
    *(bfx8*)&Bs[rowA * 32 + kb8]        = *(const bfx8*)&B[(size_t)(n0 + rowA) * 512 + k0 + kb8];
    *(bfx8*)&Bs[(rowA + 64) * 32 + kb8] = *(const bfx8*)&B[(size_t)(n0 + rowA + 64) * 512 + k0 + kb8];
    __syncthreads();
    bfx8 af[4], bf_[4];
#pragma unroll
    for (int mi = 0; mi < 4; mi++)
      af[mi] = *(const bfx8*)&As[(wm * 64 + mi * 16 + li) * 32 + lg * 8];
#pragma unroll
    for (int ni = 0; ni < 4; ni++)
      bf_[ni] = *(const bfx8*)&Bs[(wn * 64 + ni * 16 + li) * 32 + lg * 8];
#pragma unroll
    for (int mi = 0; mi < 4; mi++)
#pragma unroll
      for (int ni = 0; ni < 4; ni++)
        acc[mi][ni] = __builtin_amdgcn_mfma_f32_16x16x32_bf16(af[mi], bf_[ni], acc[mi][ni], 0, 0, 0);
  }
#pragma unroll
  for (int mi = 0; mi < 4; mi++) {
#pragma unroll
    for (int ni = 0; ni < 4; ni++) {
      const int nc  = n0 + wn * 64 + ni * 16 + li;
      const int mrb = m0 + wm * 64 + mi * 16 + lg * 4;
      const float bv = bias[nc];
#pragma unroll
      for (int r = 0; r < 4; r++)
        outf[(size_t)(mrb + r) * 512 + nc] = acc[mi][ni][r] + bv;
    }
  }
}

// ---------------- host ----------------
extern "C" void kernel_launch(void* const* d_in, const int* in_sizes, int n_in,
                              void* d_out, int out_size, void* d_ws, size_t ws_size,
                              hipStream_t stream) {
  const float* x      = (const float*)d_in[0];
  const float* w_qkv  = (const float*)d_in[1];
  const float* reattn = (const float*)d_in[2];
  const float* ln_g   = (const float*)d_in[3];
  const float* ln_b   = (const float*)d_in[4];
  const float* w_out  = (const float*)d_in[5];
  const float* b_out  = (const float*)d_in[6];
  float* out = (float*)d_out;
  char* ws = (char*)d_ws;
  // ws layout (bytes), ~22.5 MB:
  //  [0, 8388608)  : xb + wqb during k0/k1; then innerF f32 (zeroed after k1).
  //  innerB bf16 reuses qbf region after passB completes.
  u16*    xb    = (u16*)(ws + 0);
  u16*    wqb   = (u16*)(ws + 4194304);
  float*  innerF= (float*)(ws + 0);
  u16*    qbf   = (u16*)(ws + 8388608);    // [2,8,2048,64] bf16 (scaled)
  u16*    kbf   = (u16*)(ws + 12582912);   // [2,8,2048,64] bf16
  u16*    vtb   = (u16*)(ws + 16777216);   // [2,8,64,2048] bf16
  float2* statp = (float2*)(ws + 20971520);// [4][2,8,2048] raw (m, l) partials
  u16*    wob   = (u16*)(ws + 22020096);   // 512x512 bf16
  u16*    innerB= (u16*)(ws + 8388608);    // reuses qbf after passB

  convert3<<<3072, 256, 0, stream>>>(x, w_qkv, w_out, xb, wqb, wob);
  gemm_qkv<<<dim3(12, 32), 256, 0, stream>>>(xb, wqb, qbf, kbf, vtb);
  hipMemsetAsync(innerF, 0, 8388608, stream);
  passA<<<dim3(32, 16, 4), 256, 0, stream>>>(qbf, kbf, statp);
  passB<<<dim3(128, 2, 4), 256, 0, stream>>>(qbf, kbf, vtb, statp, reattn, ln_g, ln_b, innerF);
  convertInner<<<2048, 256, 0, stream>>>(innerF, innerB);
  gemm_out<<<dim3(4, 32), 256, 0, stream>>>(innerB, wob, out, b_out);
}